// Round 9
// baseline (798.890 us; speedup 1.0000x reference)
//
#include <hip/hip_runtime.h>
#include <hip/hip_fp16.h>

#define N_ROWS 32768
#define KCODES 8192
#define CDIM   256
#define NSUB   (KCODES / 16)     // 512 subtiles of 16 codes
// dot-scale margin: covers bf16-dot err + fp16-RTZ storage (~3e-5) + e2 spread (<=1.9e-6).
// Certified need ~1.05e-4; rounds 2-8 passed with this exact value + raw-dot-max semantics.
#define MARGIN_DOT 2.2e-4f
#define CAP_ROW 15               // per-row candidate cap (mean 1.7); overflow -> 0xFFFF marker
#define CAP_BIN 1024             // per-subtile LDS list cap (mean ~107); overflow -> exact fallback

typedef __attribute__((ext_vector_type(8))) short bf16x8;
typedef __attribute__((ext_vector_type(4))) float f32x4;

// async global->LDS, 16B per lane; LDS dest is wave-uniform base + lane*16 (linear),
// so XOR swizzles are applied to the per-lane GLOBAL source address instead (rule #21).
#define GLOAD_LDS16(g, l)                                                              \
    __builtin_amdgcn_global_load_lds((const __attribute__((address_space(1))) void*)(g), \
                                     (__attribute__((address_space(3))) void*)(l), 16, 0, 0)

__device__ __forceinline__ ushort f2bf_rne(float f) {
    unsigned u = __float_as_uint(f);
    u += 0x7fffu + ((u >> 16) & 1u);
    return (ushort)(u >> 16);
}

// ---------- phase 0: fp32->bf16 convert + row sum-of-squares + bestG init ----------
__global__ void prep_kernel(const float* __restrict__ x, const float* __restrict__ wgt,
                            ushort* __restrict__ xb, ushort* __restrict__ wb,
                            float* __restrict__ t1, float* __restrict__ e2,
                            unsigned long long* __restrict__ bestG) {
    const int gtid = blockIdx.x * blockDim.x + threadIdx.x;
    if (gtid < N_ROWS) bestG[gtid] = ~0ull;      // init per-row best key

    int wave = gtid >> 6;
    int lane = threadIdx.x & 63;
    const float* src; ushort* bdst; float* sqdst; int row;
    if (wave < N_ROWS) { src = x; bdst = xb; sqdst = t1; row = wave; }
    else               { src = wgt; bdst = wb; sqdst = e2; row = wave - N_ROWS; }
    float4 v = *((const float4*)src + (size_t)row * (CDIM / 4) + lane);
    ushort4 o;
    o.x = f2bf_rne(v.x); o.y = f2bf_rne(v.y); o.z = f2bf_rne(v.z); o.w = f2bf_rne(v.w);
    *((ushort4*)bdst + (size_t)row * (CDIM / 4) + lane) = o;
    float s = v.x * v.x + v.y * v.y + v.z * v.z + v.w * v.w;
    for (int off = 32; off; off >>= 1) s += __shfl_down(s, off, 64);
    if (lane == 0) sqdst[row] = s;
}

// ---------- phase 1: 256x128 tile, 8 waves x (64x64), BK=32 dbuf, TRANSPOSED MFMA ----------
// Round-8 counters: MfmaUtil 36.8% = the m97-structure barrier-drain signature, Occ 42%
// (2 blocks/CU; 53.76 KB LDS missed 3 blocks by 1.3 KB). Change: mbT aliased onto xs[0]
// (only written after the K-loop's final barrier; xs[0]'s last read is chunk 6 — two
// barriers earlier; round-2-verified aliasing pattern) -> LDS 48 KB -> 3 independent
// 8-wave barrier gangs per CU; launch_bounds(512,6) (VGPR 64 <= 85 budget).
__launch_bounds__(512, 6)
__global__ void vq_mfma_kernel(const ushort* __restrict__ xb, const ushort* __restrict__ wb,
                               __half* __restrict__ minT) {
    __shared__ ushort xs[2][256 * 32];   // 2 x 16 KB  (X: 256 rows x 32 cols)
    __shared__ ushort ws_l[2][128 * 32]; // 2 x 8 KB   (W: 128 codes x 32 cols)
    // transposed maxima scratch, aliased onto xs[0] (8 x 264 x 2B = 4.125 KB)
    ushort (*mbT)[264] = (ushort (*)[264])&xs[0][0];

    const int t = threadIdx.x;
    const int w = t >> 6, lane = t & 63;
    const int ln15 = lane & 15, quad = lane >> 4;
    const int rt = blockIdx.x >> 6;     // 128 row tiles
    const int ct = blockIdx.x & 63;     // 64 code tiles
    const int rbase = (w >> 1) * 64;    // wave x-row base (0/64/128/192)
    const int cbase = (w & 1) * 64;     // wave code base (0 or 64)

    const int srow16 = lane >> 2;
    const int schunk = (lane & 3) ^ ((lane >> 3) & 3);   // pre-swizzled source 16B chunk
    const ushort* xsrc = xb + (size_t)(rt * 256 + w * 32 + srow16) * CDIM + schunk * 8;
    const ushort* wsrc = wb + (size_t)(ct * 128 + w * 16 + srow16) * CDIM + schunk * 8;

    f32x4 acc[4][4];                    // [ni: code blocks][mi: x-row blocks]
#pragma unroll
    for (int ni = 0; ni < 4; ++ni)
#pragma unroll
        for (int mi = 0; mi < 4; ++mi)
#pragma unroll
            for (int r = 0; r < 4; ++r) acc[ni][mi][r] = 0.f;

#pragma unroll
    for (int j = 0; j < 2; ++j)
        GLOAD_LDS16(xsrc + (size_t)j * 16 * CDIM, &xs[0][(w * 32 + j * 16) * 32]);
    GLOAD_LDS16(wsrc, &ws_l[0][(w * 16) * 32]);
    __syncthreads();

#pragma unroll
    for (int cc = 0; cc < 8; ++cc) {                  // 8 K-chunks of 32
        const int cur = cc & 1;
        if (cc < 7) {                                  // issue next-chunk loads FIRST
#pragma unroll
            for (int j = 0; j < 2; ++j)
                GLOAD_LDS16(xsrc + (size_t)j * 16 * CDIM + (cc + 1) * 32,
                            &xs[cur ^ 1][(w * 32 + j * 16) * 32]);
            GLOAD_LDS16(wsrc + (cc + 1) * 32, &ws_l[cur ^ 1][(w * 16) * 32]);
        }
        const int swz = (quad ^ ((ln15 >> 1) & 3)) * 8;
        bf16x8 a[4], b[4];
#pragma unroll
        for (int ni = 0; ni < 4; ++ni)
            a[ni] = *(const bf16x8*)&ws_l[cur][(cbase + ni * 16 + ln15) * 32 + swz];
#pragma unroll
        for (int mi = 0; mi < 4; ++mi)
            b[mi] = *(const bf16x8*)&xs[cur][(rbase + mi * 16 + ln15) * 32 + swz];
#pragma unroll
        for (int ni = 0; ni < 4; ++ni)
#pragma unroll
            for (int mi = 0; mi < 4; ++mi)
                acc[ni][mi] = __builtin_amdgcn_mfma_f32_16x16x32_bf16(a[ni], b[mi], acc[ni][mi], 0, 0, 0);
        __syncthreads();          // drains vmcnt -> buf^1 ready; protects buf reuse
    }
    // xs[0] last READ was chunk 6 (chunk 7 reads xs[1]); all waves passed chunk 7's
    // barrier above -> mbT (alias of xs[0]) writes below are race-free.

    // epilogue (verified rounds 3-8): codes live in {regs x quads}
#pragma unroll
    for (int mi = 0; mi < 4; ++mi) {
        float mxn[4];
#pragma unroll
        for (int ni = 0; ni < 4; ++ni) {
            f32x4 v = acc[ni][mi];
            float mx = fmaxf(fmaxf(v[0], v[1]), fmaxf(v[2], v[3]));
            mx = fmaxf(mx, __shfl_xor(mx, 16, 64));
            mx = fmaxf(mx, __shfl_xor(mx, 32, 64));
            mxn[ni] = mx;
        }
        float sel = quad == 0 ? mxn[0] : quad == 1 ? mxn[1] : quad == 2 ? mxn[2] : mxn[3];
        uint pk = __builtin_bit_cast(uint, __builtin_amdgcn_cvt_pkrtz(sel, sel));  // RTZ as certified
        mbT[(cbase >> 4) + quad][rbase + mi * 16 + ln15] = (ushort)(pk & 0xffffu);
    }
    __syncthreads();
    if (t < 256) {
        union { ushort s[8]; uint4 u; } r;
#pragma unroll
        for (int s = 0; s < 8; ++s) r.s[s] = mbT[s][t];
        *(uint4*)(minT + ((size_t)(rt * 64 + ct) * 256 + t) * 8) = r.u;
    }
}

// ---------- phase 2a: candidate scan -> packed per-row records (NO global atomics) ----------
// Round-8 traffic analysis: the direct minT read was 64 lanes x 16B at 4KB stride ->
// 16B used per 64B line = 4x fetch amplification on 32 MB. This version block-stages
// the 16-row slice of all 64 ct-panels via contiguous 256B runs into LDS (17 KB), then
// runs the BIT-IDENTICAL threshold math from LDS (same values, same lane mapping, same
// order). ct stride padded to 136 ushorts -> residual LDS conflicts ~8-way on 16 reads.
__launch_bounds__(256, 8)
__global__ void vq_scan_kernel(const __half* __restrict__ minT, uint* __restrict__ rowcand) {
    __shared__ ushort sm[64][136];       // [ct][row*8+sub], padded stride (17 KB)
    __shared__ ushort cand[16][16];      // [row][0]=cnt/marker, [row][1..15]=subtile ids
    const int t = threadIdx.x, w = t >> 6, lane = t & 63;
    const int row0 = blockIdx.x * 16;

    // stage: thread t covers ct = t>>2, rows 4*(t&3)..+4 (64B contiguous per thread)
    {
        const int ct = t >> 2, c4 = t & 3;
        const uint4* src = (const uint4*)(minT +
            ((((size_t)(row0 >> 8) * 64 + ct) * 256 + (row0 & 255) + c4 * 4) * 8));
#pragma unroll
        for (int i = 0; i < 4; ++i)
            *(uint4*)&sm[ct][(c4 * 4 + i) * 8] = src[i];
    }
    __syncthreads();

    for (int i = 0; i < 4; ++i) {
        const int rr = w * 4 + i;
        union { uint4 u; __half2 h2[4]; } raw;
        raw.u = *(const uint4*)&sm[lane][rr * 8];    // same values as the old global read
        float m[8];
#pragma unroll
        for (int q = 0; q < 4; ++q) {
            float2 f = __half22float2(raw.h2[q]);
            m[2 * q] = f.x;
            m[2 * q + 1] = f.y;
        }
        float lmax = m[0];
#pragma unroll
        for (int q = 1; q < 8; ++q) lmax = fmaxf(lmax, m[q]);
#pragma unroll
        for (int off = 1; off < 64; off <<= 1) lmax = fmaxf(lmax, __shfl_xor(lmax, off, 64));
        const float thresh = lmax - MARGIN_DOT;

        int base = 0;
#pragma unroll
        for (int s = 0; s < 8; ++s) {
            bool c = (m[s] >= thresh);
            unsigned long long mask = __ballot(c);
            if (c) {
                int pos = base + (int)__popcll(mask & ((1ull << lane) - 1ull));
                if (pos < CAP_ROW) cand[rr][1 + pos] = (ushort)(lane * 8 + s);
            }
            base += (int)__popcll(mask);
        }
        if (lane == 0) cand[rr][0] = (base <= CAP_ROW) ? (ushort)base : (ushort)0xffff;
    }
    __syncthreads();
    if (t < 128)   // 16 rows x 32B, coalesced
        rowcand[(size_t)(row0 + (t >> 3)) * 8 + (t & 7)] = ((const uint*)cand)[t];
}

// ---------- phase 2b: per-subtile exact fp32 rerank (block = subtile) ----------
// (unchanged from round 8, which passed)
__launch_bounds__(512, 4)
__global__ void vq_subproc_kernel(const float* __restrict__ x, const float* __restrict__ wgt,
                                  const float* __restrict__ t1, const float* __restrict__ e2,
                                  const uint* __restrict__ rowcand,
                                  unsigned long long* __restrict__ bestG) {
    __shared__ float wsub[16][260];     // 16 codes x 256 floats (+4 pad)
    __shared__ float xbuf[32][264];     // one x row per 16-lane group (+8 pad)
    __shared__ int list[CAP_BIN];
    __shared__ int nlist;

    const int t = threadIdx.x;
    const int g = t >> 4, gl = t & 15;              // 32 groups x 16 lanes
    const int st = blockIdx.x;                      // subtile id

    if (t == 0) nlist = 0;
#pragma unroll
    for (int j = 0; j < 2; ++j) {
        const int idx = t + 512 * j;                // code = idx>>6, chunk = idx&63
        *(float4*)&wsub[idx >> 6][(idx & 63) * 4] =
            ((const float4*)(wgt + (size_t)(st * 16 + (idx >> 6)) * CDIM))[idx & 63];
    }
    const float e2v = e2[st * 16 + gl];
    __syncthreads();

    // membership scan: thread handles rows t, t+512, ... (64 iterations)
    for (int it = 0; it < 64; ++it) {
        const int r = t + 512 * it;
        union { struct { uint4 a, b; } qq; ushort h[16]; } rc;
        rc.qq.a = ((const uint4*)rowcand)[(size_t)r * 2];
        rc.qq.b = ((const uint4*)rowcand)[(size_t)r * 2 + 1];
        const uint cnt = rc.h[0];
        bool match = (cnt == 0xffffu);              // marker: candidate everywhere
        const int n = cnt < (uint)CAP_ROW ? (int)cnt : CAP_ROW;
#pragma unroll
        for (int j = 0; j < CAP_ROW; ++j)
            match |= (j < n) && (rc.h[1 + j] == (ushort)st);
        if (match) {
            const int pos = atomicAdd(&nlist, 1);   // LDS atomic (cheap; r3-8 pattern)
            if (pos < CAP_BIN) {
                list[pos] = r;
            } else {
                // overflow fallback (never expected): serial exact rerank of row r
                const float* xp = x + (size_t)r * CDIM;
                const float t1r = t1[r];
                unsigned long long bk = ~0ull;
                for (int kk = 0; kk < 16; ++kk) {
                    float acc = 0.f;
                    for (int c = 0; c < CDIM; ++c) acc = fmaf(xp[c], wsub[kk][c], acc);
                    float d = (t1r + e2[st * 16 + kk]) - 2.0f * acc;
                    unsigned long long key =
                        ((unsigned long long)__float_as_uint(d) << 32) | (uint)(st * 16 + kk);
                    bk = key < bk ? key : bk;
                }
                atomicMin(&bestG[r], bk);
            }
        }
    }
    __syncthreads();

    const int cnt = nlist < CAP_BIN ? nlist : CAP_BIN;
    for (int base = 0; base < cnt; base += 32) {
        const int e = base + g;
        const bool valid = e < cnt;
        int row = 0;
        if (valid) {
            row = list[e];
            const float4* xs = (const float4*)(x + (size_t)row * CDIM);
#pragma unroll
            for (int j = 0; j < 4; ++j)
                *(float4*)&xbuf[g][(gl + 16 * j) * 4] = xs[gl + 16 * j];
        }
        unsigned long long key = ~0ull;
        if (valid) {
            // EXACT accumulation order: sequential c = 0..255, fmaf chain (unchanged).
            float acc = 0.f;
#pragma unroll
            for (int c4 = 0; c4 < 64; ++c4) {
                const float4 wv = *(const float4*)&wsub[gl][c4 * 4];
                const float4 xv = *(const float4*)&xbuf[g][c4 * 4];
                acc = fmaf(xv.x, wv.x, acc);
                acc = fmaf(xv.y, wv.y, acc);
                acc = fmaf(xv.z, wv.z, acc);
                acc = fmaf(xv.w, wv.w, acc);
            }
            const int k = st * 16 + gl;
            float d = (t1[row] + e2v) - 2.0f * acc;  // exact, same chain as rounds 1-8
            key = ((unsigned long long)__float_as_uint(d) << 32) | (uint)k;
        }
#pragma unroll
        for (int off = 1; off < 16; off <<= 1) {
            unsigned long long ok = __shfl_xor(key, off, 64);
            key = ok < key ? ok : key;
        }
        if (gl == 0 && valid) atomicMin(&bestG[row], key);  // scattered: fast (r7/r8-validated)
    }
}

// ---------- phase 2c: index write + fused gather (unchanged, validated) ----------
__launch_bounds__(256, 8)
__global__ void vq_gather_kernel(const float* __restrict__ wgt,
                                 const unsigned long long* __restrict__ bestG,
                                 float* __restrict__ out_q, float* __restrict__ out_i) {
    const int t = threadIdx.x;
    const int g = t >> 4, gl = t & 15;
    const int row = blockIdx.x * 16 + g;
    const int bk = (int)(uint)(bestG[row] & 0xffffffffu);
    if (gl == 0) out_i[row] = (float)bk;
    const float4* src = (const float4*)(wgt + (size_t)bk * CDIM);
    float4* dst = (float4*)(out_q + (size_t)row * CDIM);
#pragma unroll
    for (int j = 0; j < 4; ++j) dst[gl + 16 * j] = src[gl + 16 * j];
}

extern "C" void kernel_launch(void* const* d_in, const int* in_sizes, int n_in,
                              void* d_out, int out_size, void* d_ws, size_t ws_size,
                              hipStream_t stream) {
    const float* x = (const float*)d_in[0];   // (8,4096,256) fp32
    const float* wgt = (const float*)d_in[1]; // (8192,256) fp32

    float* out_q = (float*)d_out;
    float* out_i = out_q + (size_t)N_ROWS * CDIM;

    // workspace carve (all 16B aligned): ~53.9 MB total
    char* p = (char*)d_ws;
    float* e2 = (float*)p;                     p += (size_t)KCODES * 4;
    float* t1 = (float*)p;                     p += (size_t)N_ROWS * 4;
    __half* minT = (__half*)p;                 p += (size_t)N_ROWS * NSUB * 2;
    ushort* xb = (ushort*)p;                   p += (size_t)N_ROWS * CDIM * 2;
    ushort* wb = (ushort*)p;                   p += (size_t)KCODES * CDIM * 2;
    unsigned long long* bestG = (unsigned long long*)p; p += (size_t)N_ROWS * 8;
    uint* rowcand = (uint*)p;                  p += (size_t)N_ROWS * 32;

    prep_kernel<<<(N_ROWS + KCODES) / 4, 256, 0, stream>>>(x, wgt, xb, wb, t1, e2, bestG);
    vq_mfma_kernel<<<(N_ROWS / 256) * (KCODES / 128), 512, 0, stream>>>(xb, wb, minT);
    vq_scan_kernel<<<N_ROWS / 16, 256, 0, stream>>>(minT, rowcand);
    vq_subproc_kernel<<<NSUB, 512, 0, stream>>>(x, wgt, t1, e2, rowcand, bestG);
    vq_gather_kernel<<<N_ROWS / 16, 256, 0, stream>>>(wgt, bestG, out_q, out_i);
}

// Round 10
// 347.149 us; speedup vs baseline: 2.3013x; 2.3013x over previous
//
#include <hip/hip_runtime.h>
#include <hip/hip_fp16.h>

#define N_ROWS 32768
#define KCODES 8192
#define CDIM   256
#define NSUB   (KCODES / 16)     // 512 subtiles of 16 codes
// dot-scale margin: covers bf16-dot err + fp16-RTZ storage (~3e-5) + e2 spread (<=1.9e-6).
// Certified need ~1.05e-4; rounds 2-9 passed with this exact value + raw-dot-max semantics.
#define MARGIN_DOT 2.2e-4f
#define CAP_ROW 15               // per-row candidate cap (mean 1.7); overflow -> 0xFFFF marker
#define CAP_BIN 1024             // per-subtile LDS list cap (mean ~107); overflow -> exact fallback

typedef __attribute__((ext_vector_type(8))) short bf16x8;
typedef __attribute__((ext_vector_type(4))) float f32x4;

// async global->LDS, 16B per lane; LDS dest is wave-uniform base + lane*16 (linear),
// so XOR swizzles are applied to the per-lane GLOBAL source address instead (rule #21).
#define GLOAD_LDS16(g, l)                                                              \
    __builtin_amdgcn_global_load_lds((const __attribute__((address_space(1))) void*)(g), \
                                     (__attribute__((address_space(3))) void*)(l), 16, 0, 0)

__device__ __forceinline__ ushort f2bf_rne(float f) {
    unsigned u = __float_as_uint(f);
    u += 0x7fffu + ((u >> 16) & 1u);
    return (ushort)(u >> 16);
}

// ---------- phase 0: fp32->bf16 convert + row sum-of-squares + bestG init ----------
__global__ void prep_kernel(const float* __restrict__ x, const float* __restrict__ wgt,
                            ushort* __restrict__ xb, ushort* __restrict__ wb,
                            float* __restrict__ t1, float* __restrict__ e2,
                            unsigned long long* __restrict__ bestG) {
    const int gtid = blockIdx.x * blockDim.x + threadIdx.x;
    if (gtid < N_ROWS) bestG[gtid] = ~0ull;      // init per-row best key

    int wave = gtid >> 6;
    int lane = threadIdx.x & 63;
    const float* src; ushort* bdst; float* sqdst; int row;
    if (wave < N_ROWS) { src = x; bdst = xb; sqdst = t1; row = wave; }
    else               { src = wgt; bdst = wb; sqdst = e2; row = wave - N_ROWS; }
    float4 v = *((const float4*)src + (size_t)row * (CDIM / 4) + lane);
    ushort4 o;
    o.x = f2bf_rne(v.x); o.y = f2bf_rne(v.y); o.z = f2bf_rne(v.z); o.w = f2bf_rne(v.w);
    *((ushort4*)bdst + (size_t)row * (CDIM / 4) + lane) = o;
    float s = v.x * v.x + v.y * v.y + v.z * v.z + v.w * v.w;
    for (int off = 32; off; off >>= 1) s += __shfl_down(s, off, 64);
    if (lane == 0) sqdst[row] = s;
}

// ---------- phase 1: 256x128 tile, 8 waves x (64x64), BK=32 dbuf, TRANSPOSED MFMA ----------
// Round-9 lesson: launch_bounds(512,6) capped the allocator at ~85 VGPR -> accumulator
// SPILL (VGPR 40, FETCH 916 MB, 624 us). Fix: keep the mbT-on-xs[0] alias (LDS 48 KB)
// but revert to (512,3): the r8 codegen (VGPR 64, no spill) returns, and HW occupancy
// is LDS-bound at 3 blocks/CU = 24 waves — the third independent barrier gang — without
// constraining the register allocator (launch_bounds only needs to PERMIT the occupancy).
__launch_bounds__(512, 3)
__global__ void vq_mfma_kernel(const ushort* __restrict__ xb, const ushort* __restrict__ wb,
                               __half* __restrict__ minT) {
    __shared__ ushort xs[2][256 * 32];   // 2 x 16 KB  (X: 256 rows x 32 cols)
    __shared__ ushort ws_l[2][128 * 32]; // 2 x 8 KB   (W: 128 codes x 32 cols)
    // transposed maxima scratch, aliased onto xs[0] (8 x 264 x 2B = 4.125 KB).
    // Safe: xs[0]'s last READ is chunk 6 (chunk 7 reads xs[1]); every wave passes
    // chunk 7's barrier before any mbT write (r8/r9-verified correct).
    ushort (*mbT)[264] = (ushort (*)[264])&xs[0][0];

    const int t = threadIdx.x;
    const int w = t >> 6, lane = t & 63;
    const int ln15 = lane & 15, quad = lane >> 4;
    const int rt = blockIdx.x >> 6;     // 128 row tiles
    const int ct = blockIdx.x & 63;     // 64 code tiles
    const int rbase = (w >> 1) * 64;    // wave x-row base (0/64/128/192)
    const int cbase = (w & 1) * 64;     // wave code base (0 or 64)

    const int srow16 = lane >> 2;
    const int schunk = (lane & 3) ^ ((lane >> 3) & 3);   // pre-swizzled source 16B chunk
    const ushort* xsrc = xb + (size_t)(rt * 256 + w * 32 + srow16) * CDIM + schunk * 8;
    const ushort* wsrc = wb + (size_t)(ct * 128 + w * 16 + srow16) * CDIM + schunk * 8;

    f32x4 acc[4][4];                    // [ni: code blocks][mi: x-row blocks]
#pragma unroll
    for (int ni = 0; ni < 4; ++ni)
#pragma unroll
        for (int mi = 0; mi < 4; ++mi)
#pragma unroll
            for (int r = 0; r < 4; ++r) acc[ni][mi][r] = 0.f;

#pragma unroll
    for (int j = 0; j < 2; ++j)
        GLOAD_LDS16(xsrc + (size_t)j * 16 * CDIM, &xs[0][(w * 32 + j * 16) * 32]);
    GLOAD_LDS16(wsrc, &ws_l[0][(w * 16) * 32]);
    __syncthreads();

#pragma unroll
    for (int cc = 0; cc < 8; ++cc) {                  // 8 K-chunks of 32
        const int cur = cc & 1;
        if (cc < 7) {                                  // issue next-chunk loads FIRST
#pragma unroll
            for (int j = 0; j < 2; ++j)
                GLOAD_LDS16(xsrc + (size_t)j * 16 * CDIM + (cc + 1) * 32,
                            &xs[cur ^ 1][(w * 32 + j * 16) * 32]);
            GLOAD_LDS16(wsrc + (cc + 1) * 32, &ws_l[cur ^ 1][(w * 16) * 32]);
        }
        const int swz = (quad ^ ((ln15 >> 1) & 3)) * 8;
        bf16x8 a[4], b[4];
#pragma unroll
        for (int ni = 0; ni < 4; ++ni)
            a[ni] = *(const bf16x8*)&ws_l[cur][(cbase + ni * 16 + ln15) * 32 + swz];
#pragma unroll
        for (int mi = 0; mi < 4; ++mi)
            b[mi] = *(const bf16x8*)&xs[cur][(rbase + mi * 16 + ln15) * 32 + swz];
#pragma unroll
        for (int ni = 0; ni < 4; ++ni)
#pragma unroll
            for (int mi = 0; mi < 4; ++mi)
                acc[ni][mi] = __builtin_amdgcn_mfma_f32_16x16x32_bf16(a[ni], b[mi], acc[ni][mi], 0, 0, 0);
        __syncthreads();          // drains vmcnt -> buf^1 ready; protects buf reuse
    }

    // epilogue (verified rounds 3-9): codes live in {regs x quads}
#pragma unroll
    for (int mi = 0; mi < 4; ++mi) {
        float mxn[4];
#pragma unroll
        for (int ni = 0; ni < 4; ++ni) {
            f32x4 v = acc[ni][mi];
            float mx = fmaxf(fmaxf(v[0], v[1]), fmaxf(v[2], v[3]));
            mx = fmaxf(mx, __shfl_xor(mx, 16, 64));
            mx = fmaxf(mx, __shfl_xor(mx, 32, 64));
            mxn[ni] = mx;
        }
        float sel = quad == 0 ? mxn[0] : quad == 1 ? mxn[1] : quad == 2 ? mxn[2] : mxn[3];
        uint pk = __builtin_bit_cast(uint, __builtin_amdgcn_cvt_pkrtz(sel, sel));  // RTZ as certified
        mbT[(cbase >> 4) + quad][rbase + mi * 16 + ln15] = (ushort)(pk & 0xffffu);
    }
    __syncthreads();
    if (t < 256) {
        union { ushort s[8]; uint4 u; } r;
#pragma unroll
        for (int s = 0; s < 8; ++s) r.s[s] = mbT[s][t];
        *(uint4*)(minT + ((size_t)(rt * 64 + ct) * 256 + t) * 8) = r.u;
    }
}

// ---------- phase 2a: candidate scan -> packed per-row records (NO global atomics) ----------
// (unchanged from round 9, which passed: LDS-staged minT read kills the 4x fetch
// amplification; threshold math BIT-IDENTICAL to rounds 2-9)
__launch_bounds__(256, 8)
__global__ void vq_scan_kernel(const __half* __restrict__ minT, uint* __restrict__ rowcand) {
    __shared__ ushort sm[64][136];       // [ct][row*8+sub], padded stride (17 KB)
    __shared__ ushort cand[16][16];      // [row][0]=cnt/marker, [row][1..15]=subtile ids
    const int t = threadIdx.x, w = t >> 6, lane = t & 63;
    const int row0 = blockIdx.x * 16;

    // stage: thread t covers ct = t>>2, rows 4*(t&3)..+4 (64B contiguous per thread)
    {
        const int ct = t >> 2, c4 = t & 3;
        const uint4* src = (const uint4*)(minT +
            ((((size_t)(row0 >> 8) * 64 + ct) * 256 + (row0 & 255) + c4 * 4) * 8));
#pragma unroll
        for (int i = 0; i < 4; ++i)
            *(uint4*)&sm[ct][(c4 * 4 + i) * 8] = src[i];
    }
    __syncthreads();

    for (int i = 0; i < 4; ++i) {
        const int rr = w * 4 + i;
        union { uint4 u; __half2 h2[4]; } raw;
        raw.u = *(const uint4*)&sm[lane][rr * 8];    // same values as the old global read
        float m[8];
#pragma unroll
        for (int q = 0; q < 4; ++q) {
            float2 f = __half22float2(raw.h2[q]);
            m[2 * q] = f.x;
            m[2 * q + 1] = f.y;
        }
        float lmax = m[0];
#pragma unroll
        for (int q = 1; q < 8; ++q) lmax = fmaxf(lmax, m[q]);
#pragma unroll
        for (int off = 1; off < 64; off <<= 1) lmax = fmaxf(lmax, __shfl_xor(lmax, off, 64));
        const float thresh = lmax - MARGIN_DOT;

        int base = 0;
#pragma unroll
        for (int s = 0; s < 8; ++s) {
            bool c = (m[s] >= thresh);
            unsigned long long mask = __ballot(c);
            if (c) {
                int pos = base + (int)__popcll(mask & ((1ull << lane) - 1ull));
                if (pos < CAP_ROW) cand[rr][1 + pos] = (ushort)(lane * 8 + s);
            }
            base += (int)__popcll(mask);
        }
        if (lane == 0) cand[rr][0] = (base <= CAP_ROW) ? (ushort)base : (ushort)0xffff;
    }
    __syncthreads();
    if (t < 128)   // 16 rows x 32B, coalesced
        rowcand[(size_t)(row0 + (t >> 3)) * 8 + (t & 7)] = ((const uint*)cand)[t];
}

// ---------- phase 2b: per-subtile exact fp32 rerank (block = subtile) ----------
// (unchanged from rounds 8-9, which passed)
__launch_bounds__(512, 4)
__global__ void vq_subproc_kernel(const float* __restrict__ x, const float* __restrict__ wgt,
                                  const float* __restrict__ t1, const float* __restrict__ e2,
                                  const uint* __restrict__ rowcand,
                                  unsigned long long* __restrict__ bestG) {
    __shared__ float wsub[16][260];     // 16 codes x 256 floats (+4 pad)
    __shared__ float xbuf[32][264];     // one x row per 16-lane group (+8 pad)
    __shared__ int list[CAP_BIN];
    __shared__ int nlist;

    const int t = threadIdx.x;
    const int g = t >> 4, gl = t & 15;              // 32 groups x 16 lanes
    const int st = blockIdx.x;                      // subtile id

    if (t == 0) nlist = 0;
#pragma unroll
    for (int j = 0; j < 2; ++j) {
        const int idx = t + 512 * j;                // code = idx>>6, chunk = idx&63
        *(float4*)&wsub[idx >> 6][(idx & 63) * 4] =
            ((const float4*)(wgt + (size_t)(st * 16 + (idx >> 6)) * CDIM))[idx & 63];
    }
    const float e2v = e2[st * 16 + gl];
    __syncthreads();

    // membership scan: thread handles rows t, t+512, ... (64 iterations)
    for (int it = 0; it < 64; ++it) {
        const int r = t + 512 * it;
        union { struct { uint4 a, b; } qq; ushort h[16]; } rc;
        rc.qq.a = ((const uint4*)rowcand)[(size_t)r * 2];
        rc.qq.b = ((const uint4*)rowcand)[(size_t)r * 2 + 1];
        const uint cnt = rc.h[0];
        bool match = (cnt == 0xffffu);              // marker: candidate everywhere
        const int n = cnt < (uint)CAP_ROW ? (int)cnt : CAP_ROW;
#pragma unroll
        for (int j = 0; j < CAP_ROW; ++j)
            match |= (j < n) && (rc.h[1 + j] == (ushort)st);
        if (match) {
            const int pos = atomicAdd(&nlist, 1);   // LDS atomic (cheap; r3-9 pattern)
            if (pos < CAP_BIN) {
                list[pos] = r;
            } else {
                // overflow fallback (never expected): serial exact rerank of row r
                const float* xp = x + (size_t)r * CDIM;
                const float t1r = t1[r];
                unsigned long long bk = ~0ull;
                for (int kk = 0; kk < 16; ++kk) {
                    float acc = 0.f;
                    for (int c = 0; c < CDIM; ++c) acc = fmaf(xp[c], wsub[kk][c], acc);
                    float d = (t1r + e2[st * 16 + kk]) - 2.0f * acc;
                    unsigned long long key =
                        ((unsigned long long)__float_as_uint(d) << 32) | (uint)(st * 16 + kk);
                    bk = key < bk ? key : bk;
                }
                atomicMin(&bestG[r], bk);
            }
        }
    }
    __syncthreads();

    const int cnt = nlist < CAP_BIN ? nlist : CAP_BIN;
    for (int base = 0; base < cnt; base += 32) {
        const int e = base + g;
        const bool valid = e < cnt;
        int row = 0;
        if (valid) {
            row = list[e];
            const float4* xs = (const float4*)(x + (size_t)row * CDIM);
#pragma unroll
            for (int j = 0; j < 4; ++j)
                *(float4*)&xbuf[g][(gl + 16 * j) * 4] = xs[gl + 16 * j];
        }
        unsigned long long key = ~0ull;
        if (valid) {
            // EXACT accumulation order: sequential c = 0..255, fmaf chain (unchanged).
            float acc = 0.f;
#pragma unroll
            for (int c4 = 0; c4 < 64; ++c4) {
                const float4 wv = *(const float4*)&wsub[gl][c4 * 4];
                const float4 xv = *(const float4*)&xbuf[g][c4 * 4];
                acc = fmaf(xv.x, wv.x, acc);
                acc = fmaf(xv.y, wv.y, acc);
                acc = fmaf(xv.z, wv.z, acc);
                acc = fmaf(xv.w, wv.w, acc);
            }
            const int k = st * 16 + gl;
            float d = (t1[row] + e2v) - 2.0f * acc;  // exact, same chain as rounds 1-9
            key = ((unsigned long long)__float_as_uint(d) << 32) | (uint)k;
        }
#pragma unroll
        for (int off = 1; off < 16; off <<= 1) {
            unsigned long long ok = __shfl_xor(key, off, 64);
            key = ok < key ? ok : key;
        }
        if (gl == 0 && valid) atomicMin(&bestG[row], key);  // scattered: fast (r7-9 validated)
    }
}

// ---------- phase 2c: index write + fused gather (unchanged, validated) ----------
__launch_bounds__(256, 8)
__global__ void vq_gather_kernel(const float* __restrict__ wgt,
                                 const unsigned long long* __restrict__ bestG,
                                 float* __restrict__ out_q, float* __restrict__ out_i) {
    const int t = threadIdx.x;
    const int g = t >> 4, gl = t & 15;
    const int row = blockIdx.x * 16 + g;
    const int bk = (int)(uint)(bestG[row] & 0xffffffffu);
    if (gl == 0) out_i[row] = (float)bk;
    const float4* src = (const float4*)(wgt + (size_t)bk * CDIM);
    float4* dst = (float4*)(out_q + (size_t)row * CDIM);
#pragma unroll
    for (int j = 0; j < 4; ++j) dst[gl + 16 * j] = src[gl + 16 * j];
}

extern "C" void kernel_launch(void* const* d_in, const int* in_sizes, int n_in,
                              void* d_out, int out_size, void* d_ws, size_t ws_size,
                              hipStream_t stream) {
    const float* x = (const float*)d_in[0];   // (8,4096,256) fp32
    const float* wgt = (const float*)d_in[1]; // (8192,256) fp32

    float* out_q = (float*)d_out;
    float* out_i = out_q + (size_t)N_ROWS * CDIM;

    // workspace carve (all 16B aligned): ~53.9 MB total
    char* p = (char*)d_ws;
    float* e2 = (float*)p;                     p += (size_t)KCODES * 4;
    float* t1 = (float*)p;                     p += (size_t)N_ROWS * 4;
    __half* minT = (__half*)p;                 p += (size_t)N_ROWS * NSUB * 2;
    ushort* xb = (ushort*)p;                   p += (size_t)N_ROWS * CDIM * 2;
    ushort* wb = (ushort*)p;                   p += (size_t)KCODES * CDIM * 2;
    unsigned long long* bestG = (unsigned long long*)p; p += (size_t)N_ROWS * 8;
    uint* rowcand = (uint*)p;                  p += (size_t)N_ROWS * 32;

    prep_kernel<<<(N_ROWS + KCODES) / 4, 256, 0, stream>>>(x, wgt, xb, wb, t1, e2, bestG);
    vq_mfma_kernel<<<(N_ROWS / 256) * (KCODES / 128), 512, 0, stream>>>(xb, wb, minT);
    vq_scan_kernel<<<N_ROWS / 16, 256, 0, stream>>>(minT, rowcand);
    vq_subproc_kernel<<<NSUB, 512, 0, stream>>>(x, wgt, t1, e2, rowcand, bestG);
    vq_gather_kernel<<<N_ROWS / 16, 256, 0, stream>>>(wgt, bestG, out_q, out_i);
}